// Round 2
// baseline (10029.089 us; speedup 1.0000x reference)
//
#include <hip/hip_runtime.h>

typedef unsigned short u16;
typedef unsigned int u32;

using bf16x8 = __attribute__((ext_vector_type(8))) short;
using f32x4  = __attribute__((ext_vector_type(4))) float;

#define VOCAB 50000
#define VEXT  50256
#define OUT_AT_OFF 20102400L  // 400*50256

__device__ __forceinline__ u16 f2b(float f) {
  u32 x = __float_as_uint(f);
  u32 r = (x + 0x7fffu + ((x >> 16) & 1u)) >> 16;  // RNE f32->bf16
  return (u16)r;
}

__device__ __forceinline__ float fsigmoid(float x) { return 1.f / (1.f + __expf(-x)); }
__device__ __forceinline__ float ftanh(float x) { return 1.f - 2.f / (1.f + __expf(2.f * x)); }

// ---------------- generic f32 -> bf16 (with zero row padding at tail) ----------------
__global__ void k_conv(const float* __restrict__ src, u16* __restrict__ dst,
                       long realN, long totalN) {
  long i = (long)blockIdx.x * 256 + threadIdx.x;
  if (i >= totalN) return;
  float v = (i < realN) ? src[i] : 0.f;
  dst[i] = f2b(v);
}

// ---------------- embedding + g3 dot; xAll0 row layout = t*16 + b ----------------
__global__ __launch_bounds__(256) void k_prep(const int* __restrict__ tar,
                                              const float* __restrict__ emb,
                                              const float* __restrict__ g3w,
                                              u16* __restrict__ xAll0,
                                              float* __restrict__ g3dot) {
  int r = blockIdx.x;  // b*50+t
  int b = r / 50, t = r % 50;
  int tid = threadIdx.x;
  int idx = tar[r];
  __shared__ float red[256];
  float p = 0.f;
  long orow = (long)(t * 16 + b) * 512;
  for (int k = tid; k < 512; k += 256) {
    float v = (idx == 0) ? 0.f : emb[(long)idx * 512 + k];
    xAll0[orow + k] = f2b(v);
    p += v * g3w[k];
  }
  red[tid] = p; __syncthreads();
  for (int o = 128; o > 0; o >>= 1) { if (tid < o) red[tid] += red[tid + o]; __syncthreads(); }
  if (tid == 0) g3dot[r] = red[0];
}

__global__ void k_lengths(const int* __restrict__ tar, int* __restrict__ lens) {
  int b = threadIdx.x;
  if (b < 8) {
    int c = 0;
    for (int t = 0; t < 50; t++) c += (tar[b * 50 + t] > 0) ? 1 : 0;
    lens[b] = (c > 0) ? c : 1;
  }
}

__global__ __launch_bounds__(256) void k_mask(float* __restrict__ x4f,
                                              const int* __restrict__ lens) {
  int r = blockIdx.x, b = r / 50, t = r % 50;
  if (t >= lens[b])
    for (int k = threadIdx.x; k < 512; k += 256) x4f[(long)r * 512 + k] = 0.f;
}

// ---------------- single-CU GRU recurrence for one layer ----------------
// 16 waves; wave w owns output cols [w*32, w*32+32) for all 3 gates.
// Whh fragments register-resident (384 VGPR/wave). h double-buffered in LDS,
// swizzled so A-frag reads are lane-linear 16B. gh + h(f32) stay in registers.
__global__ __launch_bounds__(1024, 1) void k_rec(
    const u16* __restrict__ Whh,     // [1536][512] bf16 (this layer)
    const float* __restrict__ bhhL,  // [1536]
    const float* __restrict__ h0,    // [8][512] f32 (this layer)
    const float* __restrict__ gi,    // [896][1536] f32, bih fused, row = t*16+bb
    u16* __restrict__ xout,          // [896][512] bf16 (next layer input), row = t*16+bb
    float* __restrict__ x4f,         // [8][50][512] f32 (only when last)
    int last)
{
  __shared__ __align__(16) u16 hS[2][8192];  // swizzled: elem = ((col>>3)*16+row)*8 + (col&7)
  const int tid = threadIdx.x;
  const int w = tid >> 6, lane = tid & 63;
  const int m = lane & 15, q = lane >> 4;

  // preload B fragments: 3 gates x 2 col-tiles x 16 k-steps
  bf16x8 bw[3][2][16];
#pragma unroll
  for (int g = 0; g < 3; g++)
#pragma unroll
    for (int tc = 0; tc < 2; tc++)
#pragma unroll
      for (int ks = 0; ks < 16; ks++)
        bw[g][tc][ks] = *(const bf16x8*)(Whh + (long)(g * 512 + w * 32 + tc * 16 + m) * 512 + ks * 32 + q * 8);

  float bhr[2], bhz[2], bhn[2];
#pragma unroll
  for (int tc = 0; tc < 2; tc++) {
    int col = w * 32 + tc * 16 + m;
    bhr[tc] = bhhL[col]; bhz[tc] = bhhL[512 + col]; bhn[tc] = bhhL[1024 + col];
  }

  // init h (rows q*4+rg, this wave's cols) in registers + LDS buf0
  float hreg[2][4];
#pragma unroll
  for (int tc = 0; tc < 2; tc++)
#pragma unroll
    for (int rg = 0; rg < 4; rg++) {
      int row = q * 4 + rg, col = w * 32 + tc * 16 + m;
      float v = (row < 8) ? h0[row * 512 + col] : 0.f;
      hreg[tc][rg] = v;
      hS[0][((col >> 3) * 16 + row) * 8 + (col & 7)] = f2b(v);
    }
  __syncthreads();

  for (int t = 0; t < 50; t++) {
    // issue gi loads early (independent of h)
    float gv[3][2][4];
#pragma unroll
    for (int g = 0; g < 3; g++)
#pragma unroll
      for (int tc = 0; tc < 2; tc++)
#pragma unroll
        for (int rg = 0; rg < 4; rg++) {
          int row = q * 4 + rg, col = w * 32 + tc * 16 + m;
          gv[g][tc][rg] = gi[(long)(t * 16 + row) * 1536 + g * 512 + col];
        }

    // gh = h @ Whh^T  (A-frags from LDS, lane-linear)
    const u16* hbuf = hS[t & 1];
    f32x4 acc[3][2];
#pragma unroll
    for (int g = 0; g < 3; g++)
#pragma unroll
      for (int tc = 0; tc < 2; tc++) acc[g][tc] = {0.f, 0.f, 0.f, 0.f};
#pragma unroll
    for (int ks = 0; ks < 16; ks++) {
      bf16x8 af = *(const bf16x8*)(hbuf + ((ks * 4 + q) * 16 + m) * 8);
#pragma unroll
      for (int g = 0; g < 3; g++)
#pragma unroll
        for (int tc = 0; tc < 2; tc++)
          acc[g][tc] = __builtin_amdgcn_mfma_f32_16x16x32_bf16(af, bw[g][tc][ks], acc[g][tc], 0, 0, 0);
    }

    // elementwise entirely in-register (C-layout aligns r/z/n per lane)
    u16* hw = hS[(t + 1) & 1];
#pragma unroll
    for (int tc = 0; tc < 2; tc++) {
      int col = w * 32 + tc * 16 + m;
#pragma unroll
      for (int rg = 0; rg < 4; rg++) {
        int row = q * 4 + rg;
        float ghr = acc[0][tc][rg] + bhr[tc];
        float ghz = acc[1][tc][rg] + bhz[tc];
        float ghn = acc[2][tc][rg] + bhn[tc];
        float rr = fsigmoid(gv[0][tc][rg] + ghr);
        float zz = fsigmoid(gv[1][tc][rg] + ghz);
        float nn = ftanh(gv[2][tc][rg] + rr * ghn);
        float hnew = (1.f - zz) * nn + zz * hreg[tc][rg];
        if (row >= 8) hnew = 0.f;
        hreg[tc][rg] = hnew;
        u16 hb = f2b(hnew);
        hw[((col >> 3) * 16 + row) * 8 + (col & 7)] = hb;
        if (!last) xout[(long)(t * 16 + row) * 512 + col] = hb;
        else if (row < 8) x4f[((long)row * 50 + t) * 512 + col] = hnew;
      }
    }
    __syncthreads();
  }
}

// ---------------- generic bf16 MFMA GEMM: C[M,N] = A[Mp,K] @ Bm[Np,K]^T + bias ------
__global__ __launch_bounds__(256, 2) void k_gemm_bf16(
    const u16* __restrict__ A, const u16* __restrict__ Bm,
    const float* __restrict__ bias, float* __restrict__ C,
    int M, int N, int K, int ldc)
{
  __shared__ __align__(16) u16 As[4096];
  __shared__ __align__(16) u16 Bs[4096];
  const int tid = threadIdx.x;
  const int wv = tid >> 6, lane = tid & 63;
  const int wm = wv >> 1, wn = wv & 1;
  const int lrow = lane & 15, q = lane >> 4;
  const int m0 = blockIdx.y * 128, n0 = blockIdx.x * 128;

  f32x4 acc[4][4];
#pragma unroll
  for (int i = 0; i < 4; i++)
#pragma unroll
    for (int j = 0; j < 4; j++) acc[i][j] = {0.f, 0.f, 0.f, 0.f};

  for (int k0 = 0; k0 < K; k0 += 32) {
#pragma unroll
    for (int i = 0; i < 2; i++) {
      int c = i * 256 + tid;
      int row = c >> 2, ko = (c & 3) << 3;
      *(uint4*)(As + c * 8) = *(const uint4*)(A + (long)(m0 + row) * K + k0 + ko);
      *(uint4*)(Bs + c * 8) = *(const uint4*)(Bm + (long)(n0 + row) * K + k0 + ko);
    }
    __syncthreads();
    bf16x8 af[4], bfr[4];
#pragma unroll
    for (int i = 0; i < 4; i++) af[i] = *(const bf16x8*)(As + (wm * 64 + i * 16 + lrow) * 32 + q * 8);
#pragma unroll
    for (int j = 0; j < 4; j++) bfr[j] = *(const bf16x8*)(Bs + (wn * 64 + j * 16 + lrow) * 32 + q * 8);
#pragma unroll
    for (int i = 0; i < 4; i++)
#pragma unroll
      for (int j = 0; j < 4; j++)
        acc[i][j] = __builtin_amdgcn_mfma_f32_16x16x32_bf16(af[i], bfr[j], acc[i][j], 0, 0, 0);
    __syncthreads();
  }

#pragma unroll
  for (int i = 0; i < 4; i++) {
    int rbase = m0 + wm * 64 + i * 16 + q * 4;
#pragma unroll
    for (int j = 0; j < 4; j++) {
      int colg = n0 + wn * 64 + j * 16 + lrow;
      if (colg < N) {
        float bv = bias[colg];
#pragma unroll
        for (int rg = 0; rg < 4; rg++) {
          int rowg = rbase + rg;
          if (rowg < M) C[(long)rowg * ldc + colg] = acc[i][j][rg] + bv;
        }
      }
    }
  }
}

// ---------------- attention: scores + softmax + weighted + gate ----------------
__global__ __launch_bounds__(256) void k_attn(
    const float* __restrict__ e1, const float* __restrict__ e2,
    const float* __restrict__ enc, const float* __restrict__ x4f,
    const int* __restrict__ sou, const float* __restrict__ vw,
    const float* __restrict__ g1w, const float* __restrict__ g1b,
    const float* __restrict__ g2w, const float* __restrict__ g2b,
    const float* __restrict__ g3b, const float* __restrict__ g3dot,
    float* __restrict__ all_out, float* __restrict__ gate,
    float* __restrict__ atten_out)
{
  int r = blockIdx.x;  // b*50+t
  int b = r / 50;
  int tid = threadIdx.x;  // = s
  __shared__ float e2s[512], decs[512], at[256], red[256];
  for (int k = tid; k < 512; k += 256) {
    e2s[k] = e2[(long)r * 512 + k];
    decs[k] = x4f[(long)r * 512 + k];
  }
  __syncthreads();
  const float* erow = e1 + ((long)b * 256 + tid) * 512;
  float sc = 0.f;
#pragma unroll 4
  for (int h = 0; h < 512; h++) sc += vw[h] * ftanh(erow[h] + e2s[h]);
  if (sou[b * 256 + tid] == 0) sc = -INFINITY;

  red[tid] = sc; __syncthreads();
  for (int o = 128; o > 0; o >>= 1) { if (tid < o) red[tid] = fmaxf(red[tid], red[tid + o]); __syncthreads(); }
  float mx = red[0]; __syncthreads();
  float p = __expf(sc - mx);
  red[tid] = p; __syncthreads();
  for (int o = 128; o > 0; o >>= 1) { if (tid < o) red[tid] += red[tid + o]; __syncthreads(); }
  float S = red[0]; __syncthreads();
  float a = p / S;
  at[tid] = a;
  atten_out[(long)r * 256 + tid] = a;
  __syncthreads();

  float pg = 0.f;
  for (int h = tid; h < 512; h += 256) {
    float wsum = 0.f;
    const float* ecol = enc + (long)b * 256 * 512 + h;
    for (int s = 0; s < 256; s++) wsum += at[s] * ecol[(long)s * 512];
    all_out[(long)r * 1024 + h] = wsum;
    all_out[(long)r * 1024 + 512 + h] = decs[h];
    pg += wsum * g1w[h] + decs[h] * g2w[h];
  }
  red[tid] = pg; __syncthreads();
  for (int o = 128; o > 0; o >>= 1) { if (tid < o) red[tid] += red[tid + o]; __syncthreads(); }
  if (tid == 0) {
    float z = red[0] + g1b[0] + g2b[0] + g3dot[r] + g3b[0];
    gate[r] = 1.f / (1.f + __expf(-z));
  }
}

// ---------------- in-place masked softmax * (1-gate) over d_out logits -------------
__global__ __launch_bounds__(1024) void k_softmax(float* __restrict__ out,
                                                  const float* __restrict__ gate,
                                                  const int* __restrict__ ext) {
  int r = blockIdx.x;
  int b = r / 50;
  int tid = threadIdx.x;
  int nv = VOCAB + ext[b];
  __shared__ float red[1024];
  float* row = out + (long)r * VEXT;
  float m = -INFINITY;
  for (int c = tid; c < nv; c += 1024) m = fmaxf(m, row[c]);
  red[tid] = m; __syncthreads();
  for (int o = 512; o > 0; o >>= 1) { if (tid < o) red[tid] = fmaxf(red[tid], red[tid + o]); __syncthreads(); }
  m = red[0]; __syncthreads();
  float s = 0.f;
  for (int c = tid; c < nv; c += 1024) s += __expf(row[c] - m);
  red[tid] = s; __syncthreads();
  for (int o = 512; o > 0; o >>= 1) { if (tid < o) red[tid] += red[tid + o]; __syncthreads(); }
  float inv = (1.f - gate[r]) / red[0];
  for (int c = tid; c < VEXT; c += 1024) {
    float v = (c < nv) ? __expf(row[c] - m) * inv : 0.f;
    row[c] = v;
  }
}

// ---------------- copy mechanism scatter ----------------
__global__ void k_scatter(float* __restrict__ out, const float* __restrict__ atten,
                          const float* __restrict__ gate, const int* __restrict__ sou) {
  int r = blockIdx.x, s = threadIdx.x;
  int b = r / 50;
  float v = gate[r] * atten[(long)r * 256 + s];
  int colv = sou[b * 256 + s];
  atomicAdd(out + (long)r * VEXT + colv, v);
}

extern "C" void kernel_launch(void* const* d_in, const int* in_sizes, int n_in,
                              void* d_out, int out_size, void* d_ws, size_t ws_size,
                              hipStream_t stream) {
  (void)in_sizes; (void)n_in; (void)out_size;
  const int* sou = (const int*)d_in[0];
  const int* tar = (const int*)d_in[1];
  const float* hidden = (const float*)d_in[2];
  const float* enc = (const float*)d_in[3];
  const int* ext = (const int*)d_in[4];
  const float* emb = (const float*)d_in[5];
  const float* wih = (const float*)d_in[6];
  const float* whh = (const float*)d_in[7];
  const float* bih = (const float*)d_in[8];
  const float* bhh = (const float*)d_in[9];
  const float* fc_enc_w = (const float*)d_in[10];
  const float* fc_enc_b = (const float*)d_in[11];
  const float* fc_dec_w = (const float*)d_in[12];
  const float* fc_dec_b = (const float*)d_in[13];
  const float* v_w = (const float*)d_in[14];
  const float* w1 = (const float*)d_in[15];
  const float* b1 = (const float*)d_in[16];
  const float* w2 = (const float*)d_in[17];
  const float* b2 = (const float*)d_in[18];
  const float* g1w = (const float*)d_in[19];
  const float* g1b = (const float*)d_in[20];
  const float* g2w = (const float*)d_in[21];
  const float* g2b = (const float*)d_in[22];
  const float* g3w = (const float*)d_in[23];
  const float* g3b = (const float*)d_in[24];
  float* out = (float*)d_out;

  char* base = (char*)d_ws;
  size_t cur = 0;
  auto alloc = [&](size_t bytes) -> void* {
    void* r = base + cur;
    cur = (cur + bytes + 255) & ~(size_t)255;
    return r;
  };
  u16* wihB = (u16*)alloc(6291456);     // [4][1536][512] bf16
  u16* whhB = (u16*)alloc(6291456);
  u16* w1B  = (u16*)alloc(51511296);    // [50304][512] bf16 (padded)
  u16* encB = (u16*)alloc(2097152);     // [2048][512]
  u16* fceB = (u16*)alloc(524288);      // [512][512]
  u16* fcdB = (u16*)alloc(524288);
  u16* fo2B = (u16*)alloc(1048576);     // [512][1024]
  u16* midB = (u16*)alloc(524288);      // [512][512] (400 real)
  u16* decB = (u16*)alloc(524288);
  u16* allB = (u16*)alloc(1048576);     // [512][1024]
  u16* xA0  = (u16*)alloc(917504);      // [896][512] bf16, row = t*16+bb
  u16* xA1  = (u16*)alloc(917504);
  u16* xA2  = (u16*)alloc(917504);
  u16* xA3  = (u16*)alloc(917504);
  float* gi  = (float*)alloc(5505024);  // [896][1536] f32 (reused per layer)
  float* x4f = (float*)alloc(819200);   // [8][50][512]
  float* e1 = (float*)alloc(4194304);   // [2048][512]
  float* e2 = (float*)alloc(819200);    // [400][512]
  float* allo = (float*)alloc(1638400); // [400][1024]
  float* mid = (float*)alloc(819200);   // [400][512]
  float* g3dot = (float*)alloc(1600);
  float* gate = (float*)alloc(1600);
  int* lens = (int*)alloc(32);
  if (cur > ws_size) return;  // ws too small -> loud failure

  u16* xA[4] = {xA0, xA1, xA2, xA3};

  // weight / input conversions to bf16
  k_conv<<<12288, 256, 0, stream>>>(wih, wihB, 3145728L, 3145728L);
  k_conv<<<12288, 256, 0, stream>>>(whh, whhB, 3145728L, 3145728L);
  k_conv<<<100608, 256, 0, stream>>>(w1, w1B, 25731072L, 25755648L);
  k_conv<<<4096, 256, 0, stream>>>(enc, encB, 1048576L, 1048576L);
  k_conv<<<1024, 256, 0, stream>>>(fc_enc_w, fceB, 262144L, 262144L);
  k_conv<<<1024, 256, 0, stream>>>(fc_dec_w, fcdB, 262144L, 262144L);
  k_conv<<<2048, 256, 0, stream>>>(w2, fo2B, 524288L, 524288L);
  k_prep<<<400, 256, 0, stream>>>(tar, emb, g3w, xA0, g3dot);
  k_lengths<<<1, 64, 0, stream>>>(tar, lens);

  // GRU: per layer, gi GEMM (all timesteps) then single-CU recurrence
  for (int l = 0; l < 4; l++) {
    k_gemm_bf16<<<dim3(12, 7), 256, 0, stream>>>(
        xA[l], wihB + (long)l * 1536 * 512, bih + l * 1536, gi, 896, 1536, 512, 1536);
    k_rec<<<1, 1024, 0, stream>>>(
        whhB + (long)l * 1536 * 512, bhh + l * 1536, hidden + l * 4096, gi,
        (l < 3) ? xA[l + 1] : xA0, x4f, (l == 3) ? 1 : 0);
  }
  k_mask<<<400, 256, 0, stream>>>(x4f, lens);
  k_conv<<<1024, 256, 0, stream>>>(x4f, decB, 204800L, 262144L);

  // attention path
  k_gemm_bf16<<<dim3(4, 16), 256, 0, stream>>>(encB, fceB, fc_enc_b, e1, 2048, 512, 512, 512);
  k_gemm_bf16<<<dim3(4, 4), 256, 0, stream>>>(decB, fcdB, fc_dec_b, e2, 400, 512, 512, 512);
  k_attn<<<400, 256, 0, stream>>>(e1, e2, enc, x4f, sou, v_w, g1w, g1b, g2w, g2b, g3b,
                                  g3dot, allo, gate, out + OUT_AT_OFF);
  k_conv<<<2048, 256, 0, stream>>>(allo, allB, 409600L, 524288L);
  k_gemm_bf16<<<dim3(4, 4), 256, 0, stream>>>(allB, fo2B, b2, mid, 400, 512, 1024, 512);
  k_conv<<<1024, 256, 0, stream>>>(mid, midB, 204800L, 262144L);

  // logits -> softmax -> copy scatter
  k_gemm_bf16<<<dim3(393, 4), 256, 0, stream>>>(midB, w1B, b1, out, 400, 50256, 512, 50256);
  k_softmax<<<400, 1024, 0, stream>>>(out, gate, ext);
  k_scatter<<<400, 256, 0, stream>>>(out, out + OUT_AT_OFF, gate, sou);
}

// Round 3
// 1803.720 us; speedup vs baseline: 5.5602x; 5.5602x over previous
//
#include <hip/hip_runtime.h>

typedef unsigned short u16;
typedef unsigned int u32;

using bf16x8 = __attribute__((ext_vector_type(8))) short;
using f32x4  = __attribute__((ext_vector_type(4))) float;

#define VOCAB 50000
#define VEXT  50256
#define OUT_AT_OFF 20102400L  // 400*50256

__device__ __forceinline__ u16 f2b(float f) {
  u32 x = __float_as_uint(f);
  u32 r = (x + 0x7fffu + ((x >> 16) & 1u)) >> 16;  // RNE f32->bf16
  return (u16)r;
}

__device__ __forceinline__ float fsigmoid(float x) { return 1.f / (1.f + __expf(-x)); }
__device__ __forceinline__ float ftanh(float x) { return 1.f - 2.f / (1.f + __expf(2.f * x)); }

// ---------------- generic f32 -> bf16 (with zero row padding at tail) ----------------
__global__ void k_conv(const float* __restrict__ src, u16* __restrict__ dst,
                       long realN, long totalN) {
  long i = (long)blockIdx.x * 256 + threadIdx.x;
  if (i >= totalN) return;
  float v = (i < realN) ? src[i] : 0.f;
  dst[i] = f2b(v);
}

// ---------------- embedding + g3 dot; xAll0 row layout = t*16 + b ----------------
__global__ __launch_bounds__(256) void k_prep(const int* __restrict__ tar,
                                              const float* __restrict__ emb,
                                              const float* __restrict__ g3w,
                                              u16* __restrict__ xAll0,
                                              float* __restrict__ g3dot) {
  int r = blockIdx.x;  // b*50+t
  int b = r / 50, t = r % 50;
  int tid = threadIdx.x;
  int idx = tar[r];
  __shared__ float red[256];
  float p = 0.f;
  long orow = (long)(t * 16 + b) * 512;
  for (int k = tid; k < 512; k += 256) {
    float v = (idx == 0) ? 0.f : emb[(long)idx * 512 + k];
    xAll0[orow + k] = f2b(v);
    p += v * g3w[k];
  }
  red[tid] = p; __syncthreads();
  for (int o = 128; o > 0; o >>= 1) { if (tid < o) red[tid] += red[tid + o]; __syncthreads(); }
  if (tid == 0) g3dot[r] = red[0];
}

// zero the padding rows (t*16 + 8..15) of layer-0 input so MFMA sees no poison
__global__ void k_zpad(u16* __restrict__ xAll0) {
  int i = blockIdx.x * 256 + threadIdx.x;  // 50*8*512 = 204800
  int t = i >> 12, rem = i & 4095, row = 8 + (rem >> 9), k = rem & 511;
  xAll0[(long)(t * 16 + row) * 512 + k] = 0;
}

__global__ void k_lengths(const int* __restrict__ tar, int* __restrict__ lens) {
  int b = threadIdx.x;
  if (b < 8) {
    int c = 0;
    for (int t = 0; t < 50; t++) c += (tar[b * 50 + t] > 0) ? 1 : 0;
    lens[b] = (c > 0) ? c : 1;
  }
}

__global__ __launch_bounds__(256) void k_mask(float* __restrict__ x4f,
                                              const int* __restrict__ lens) {
  int r = blockIdx.x, b = r / 50, t = r % 50;
  if (t >= lens[b])
    for (int k = threadIdx.x; k < 512; k += 256) x4f[(long)r * 512 + k] = 0.f;
}

// ---------------- GRU recurrence: 4 WGs x 256 thr per layer ----------------
// Wave W = blockIdx.x*4 + w owns output cols [W*32, W*32+32) of all 3 gates.
// Whh fragments in 96 NAMED registers (384 VGPR/wave, 1 wave/SIMD, cap 512).
// h exchanged via 16KB global double buffer + agent-scope flags per step.

#define KS_LIST(F, g, tc) \
  F(g,tc,0) F(g,tc,1) F(g,tc,2) F(g,tc,3) F(g,tc,4) F(g,tc,5) F(g,tc,6) F(g,tc,7) \
  F(g,tc,8) F(g,tc,9) F(g,tc,10) F(g,tc,11) F(g,tc,12) F(g,tc,13) F(g,tc,14) F(g,tc,15)
#define ALL_LIST(F) \
  KS_LIST(F,0,0) KS_LIST(F,0,1) KS_LIST(F,1,0) KS_LIST(F,1,1) KS_LIST(F,2,0) KS_LIST(F,2,1)
#define DECLW(g,tc,ks) bf16x8 bw_##g##_##tc##_##ks;
#define LOADW(g,tc,ks) bw_##g##_##tc##_##ks = \
  *(const bf16x8*)(Whh + ((g)*512L + wcol0 + (tc)*16 + m) * 512L + (ks)*32 + q*8);
#define MF1(g,tc,ks,afv) acc_##g##_##tc = \
  __builtin_amdgcn_mfma_f32_16x16x32_bf16(afv, bw_##g##_##tc##_##ks, acc_##g##_##tc, 0, 0, 0);
#define MFALL(ks) { bf16x8 af_ = *(const bf16x8*)(hS + (((ks)*4 + q)*16 + m)*8); \
  MF1(0,0,ks,af_) MF1(0,1,ks,af_) MF1(1,0,ks,af_) MF1(1,1,ks,af_) MF1(2,0,ks,af_) MF1(2,1,ks,af_) }

__global__ __launch_bounds__(256, 1) void k_rec4(
    const u16* __restrict__ Whh,     // [1536][512] bf16 (this layer)
    const float* __restrict__ bhhL,  // [1536]
    const float* __restrict__ h0,    // [8][512] f32 (this layer)
    const float* __restrict__ gi,    // rows t*16+row, [.][1536] f32, bih fused
    u16* __restrict__ xout,          // [800+][512] bf16 next-layer input (row=t*16+row)
    float* __restrict__ x4f,         // [8][50][512] f32 (last layer only)
    u16* __restrict__ hG,            // [2][8192] u16 swizzled h exchange buffers
    int* __restrict__ flag,          // [50] zeroed
    int last)
{
  __shared__ __align__(16) u16 hS[8192];  // slot s=(col>>3)*16+row, 8 u16 per slot
  const int tid = threadIdx.x;
  const int p = blockIdx.x;
  const int w = tid >> 6, lane = tid & 63;
  const int m = lane & 15, q = lane >> 4;
  const int wcol0 = (p * 4 + w) * 32;

  ALL_LIST(DECLW)
  ALL_LIST(LOADW)

  float bh0_0 = bhhL[wcol0 + m],        bh0_1 = bhhL[wcol0 + 16 + m];
  float bh1_0 = bhhL[512 + wcol0 + m],  bh1_1 = bhhL[512 + wcol0 + 16 + m];
  float bh2_0 = bhhL[1024 + wcol0 + m], bh2_1 = bhhL[1024 + wcol0 + 16 + m];

  // init LDS with h0 (rows>=8 zero)
  for (int j = 0; j < 4; j++) {
    int s = j * 256 + tid;       // c8 = s>>4, row = s&15
    int c8 = s >> 4, row = s & 15;
    u16 tmp[8];
    if (row < 8) {
      const float* src = h0 + row * 512 + c8 * 8;
#pragma unroll
      for (int e = 0; e < 8; e++) tmp[e] = f2b(src[e]);
    } else {
#pragma unroll
      for (int e = 0; e < 8; e++) tmp[e] = 0;
    }
    *(uint4*)(hS + s * 8) = *(uint4*)tmp;
  }
  // own h in registers for the z*h term
  float hreg[2][4];
#pragma unroll
  for (int tc = 0; tc < 2; tc++)
#pragma unroll
    for (int rg = 0; rg < 4; rg++) {
      int row = q * 4 + rg, col = wcol0 + tc * 16 + m;
      hreg[tc][rg] = (row < 8) ? h0[row * 512 + col] : 0.f;
    }
  __syncthreads();

#pragma unroll 1
  for (int t = 0; t < 50; t++) {
    // gi loads early (independent of h)
    float gv[3][2][4];
#pragma unroll
    for (int g = 0; g < 3; g++)
#pragma unroll
      for (int tc = 0; tc < 2; tc++)
#pragma unroll
        for (int rg = 0; rg < 4; rg++)
          gv[g][tc][rg] = gi[(long)(t * 16 + q * 4 + rg) * 1536 + g * 512 + wcol0 + tc * 16 + m];

    f32x4 acc_0_0 = {0.f,0.f,0.f,0.f}, acc_0_1 = {0.f,0.f,0.f,0.f};
    f32x4 acc_1_0 = {0.f,0.f,0.f,0.f}, acc_1_1 = {0.f,0.f,0.f,0.f};
    f32x4 acc_2_0 = {0.f,0.f,0.f,0.f}, acc_2_1 = {0.f,0.f,0.f,0.f};
    MFALL(0) MFALL(1) MFALL(2) MFALL(3) MFALL(4) MFALL(5) MFALL(6) MFALL(7)
    MFALL(8) MFALL(9) MFALL(10) MFALL(11) MFALL(12) MFALL(13) MFALL(14) MFALL(15)

    u16* hw = hG + ((t + 1) & 1) * 8192;
#pragma unroll
    for (int tc = 0; tc < 2; tc++) {
      const float bhr = tc ? bh0_1 : bh0_0;
      const float bhz = tc ? bh1_1 : bh1_0;
      const float bhn = tc ? bh2_1 : bh2_0;
      const f32x4 a0 = tc ? acc_0_1 : acc_0_0;
      const f32x4 a1 = tc ? acc_1_1 : acc_1_0;
      const f32x4 a2 = tc ? acc_2_1 : acc_2_0;
      int col = wcol0 + tc * 16 + m;
#pragma unroll
      for (int rg = 0; rg < 4; rg++) {
        int row = q * 4 + rg;
        float rr = fsigmoid(gv[0][tc][rg] + a0[rg] + bhr);
        float zz = fsigmoid(gv[1][tc][rg] + a1[rg] + bhz);
        float nn = ftanh(gv[2][tc][rg] + rr * (a2[rg] + bhn));
        float hnew = (1.f - zz) * nn + zz * hreg[tc][rg];
        if (row >= 8) hnew = 0.f;
        hreg[tc][rg] = hnew;
        u16 hb = f2b(hnew);
        hw[((col >> 3) * 16 + row) * 8 + (col & 7)] = hb;
        if (!last) xout[(long)(t * 16 + row) * 512 + col] = hb;
        else if (row < 8) x4f[((long)row * 50 + t) * 512 + col] = hnew;
      }
    }
    __syncthreads();  // drains vmcnt before barrier -> slice globally complete
    if (tid == 0)
      __hip_atomic_fetch_add(flag + t, 1, __ATOMIC_RELEASE, __HIP_MEMORY_SCOPE_AGENT);

    if (t < 49) {
      if (tid == 0) {
        unsigned it = 0;
        while (__hip_atomic_load(flag + t, __ATOMIC_ACQUIRE, __HIP_MEMORY_SCOPE_AGENT) < 4) {
          __builtin_amdgcn_s_sleep(1);
          if (++it > (1u << 24)) break;  // wrong-but-terminating on logic bug
        }
      }
      __syncthreads();
      const u16* hr = hG + ((t + 1) & 1) * 8192;
#pragma unroll
      for (int j = 0; j < 4; j++) {
        int s = j * 256 + tid;
        *(uint4*)(hS + s * 8) = *(const uint4*)(hr + s * 8);
      }
      __syncthreads();
    }
  }
}

// ---------------- generic bf16 MFMA GEMM: C[M,N] = A[Mp,K] @ Bm[Np,K]^T + bias ------
__global__ __launch_bounds__(256, 2) void k_gemm_bf16(
    const u16* __restrict__ A, const u16* __restrict__ Bm,
    const float* __restrict__ bias, float* __restrict__ C,
    int M, int N, int K, int ldc)
{
  __shared__ __align__(16) u16 As[4096];
  __shared__ __align__(16) u16 Bs[4096];
  const int tid = threadIdx.x;
  const int wv = tid >> 6, lane = tid & 63;
  const int wm = wv >> 1, wn = wv & 1;
  const int lrow = lane & 15, q = lane >> 4;
  const int m0 = blockIdx.y * 128, n0 = blockIdx.x * 128;

  f32x4 acc[4][4];
#pragma unroll
  for (int i = 0; i < 4; i++)
#pragma unroll
    for (int j = 0; j < 4; j++) acc[i][j] = {0.f, 0.f, 0.f, 0.f};

  for (int k0 = 0; k0 < K; k0 += 32) {
#pragma unroll
    for (int i = 0; i < 2; i++) {
      int c = i * 256 + tid;
      int row = c >> 2, ko = (c & 3) << 3;
      *(uint4*)(As + c * 8) = *(const uint4*)(A + (long)(m0 + row) * K + k0 + ko);
      *(uint4*)(Bs + c * 8) = *(const uint4*)(Bm + (long)(n0 + row) * K + k0 + ko);
    }
    __syncthreads();
    bf16x8 af[4], bfr[4];
#pragma unroll
    for (int i = 0; i < 4; i++) af[i] = *(const bf16x8*)(As + (wm * 64 + i * 16 + lrow) * 32 + q * 8);
#pragma unroll
    for (int j = 0; j < 4; j++) bfr[j] = *(const bf16x8*)(Bs + (wn * 64 + j * 16 + lrow) * 32 + q * 8);
#pragma unroll
    for (int i = 0; i < 4; i++)
#pragma unroll
      for (int j = 0; j < 4; j++)
        acc[i][j] = __builtin_amdgcn_mfma_f32_16x16x32_bf16(af[i], bfr[j], acc[i][j], 0, 0, 0);
    __syncthreads();
  }

#pragma unroll
  for (int i = 0; i < 4; i++) {
    int rbase = m0 + wm * 64 + i * 16 + q * 4;
#pragma unroll
    for (int j = 0; j < 4; j++) {
      int colg = n0 + wn * 64 + j * 16 + lrow;
      if (colg < N) {
        float bv = bias[colg];
#pragma unroll
        for (int rg = 0; rg < 4; rg++) {
          int rowg = rbase + rg;
          if (rowg < M) C[(long)rowg * ldc + colg] = acc[i][j][rg] + bv;
        }
      }
    }
  }
}

// ---------------- attention: scores + softmax + weighted + gate ----------------
__global__ __launch_bounds__(256) void k_attn(
    const float* __restrict__ e1, const float* __restrict__ e2,
    const float* __restrict__ enc, const float* __restrict__ x4f,
    const int* __restrict__ sou, const float* __restrict__ vw,
    const float* __restrict__ g1w, const float* __restrict__ g1b,
    const float* __restrict__ g2w, const float* __restrict__ g2b,
    const float* __restrict__ g3b, const float* __restrict__ g3dot,
    float* __restrict__ all_out, float* __restrict__ gate,
    float* __restrict__ atten_out)
{
  int r = blockIdx.x;  // b*50+t
  int b = r / 50;
  int tid = threadIdx.x;  // = s
  __shared__ float e2s[512], decs[512], at[256], red[256];
  for (int k = tid; k < 512; k += 256) {
    e2s[k] = e2[(long)r * 512 + k];
    decs[k] = x4f[(long)r * 512 + k];
  }
  __syncthreads();
  const float* erow = e1 + ((long)b * 256 + tid) * 512;
  float sc = 0.f;
#pragma unroll 4
  for (int h = 0; h < 512; h++) sc += vw[h] * ftanh(erow[h] + e2s[h]);
  if (sou[b * 256 + tid] == 0) sc = -INFINITY;

  red[tid] = sc; __syncthreads();
  for (int o = 128; o > 0; o >>= 1) { if (tid < o) red[tid] = fmaxf(red[tid], red[tid + o]); __syncthreads(); }
  float mx = red[0]; __syncthreads();
  float p = __expf(sc - mx);
  red[tid] = p; __syncthreads();
  for (int o = 128; o > 0; o >>= 1) { if (tid < o) red[tid] += red[tid + o]; __syncthreads(); }
  float S = red[0]; __syncthreads();
  float a = p / S;
  at[tid] = a;
  atten_out[(long)r * 256 + tid] = a;
  __syncthreads();

  float pg = 0.f;
  for (int h = tid; h < 512; h += 256) {
    float wsum = 0.f;
    const float* ecol = enc + (long)b * 256 * 512 + h;
    for (int s = 0; s < 256; s++) wsum += at[s] * ecol[(long)s * 512];
    all_out[(long)r * 1024 + h] = wsum;
    all_out[(long)r * 1024 + 512 + h] = decs[h];
    pg += wsum * g1w[h] + decs[h] * g2w[h];
  }
  red[tid] = pg; __syncthreads();
  for (int o = 128; o > 0; o >>= 1) { if (tid < o) red[tid] += red[tid + o]; __syncthreads(); }
  if (tid == 0) {
    float z = red[0] + g1b[0] + g2b[0] + g3dot[r] + g3b[0];
    gate[r] = 1.f / (1.f + __expf(-z));
  }
}

// -------- online softmax * (1-gate) + fused copy-scatter, in place on d_out --------
__global__ __launch_bounds__(1024) void k_softsc(float* __restrict__ out,
                                                 const float* __restrict__ gate,
                                                 const int* __restrict__ ext,
                                                 const float* __restrict__ atten,
                                                 const int* __restrict__ sou) {
  int r = blockIdx.x;
  int b = r / 50;
  int tid = threadIdx.x;
  int nv = VOCAB + ext[b];
  __shared__ float redm[1024], reds[1024];
  float* row = out + (long)r * VEXT;
  float m = -INFINITY, s = 0.f;
  for (int c = tid; c < nv; c += 1024) {
    float v = row[c];
    float nm = fmaxf(m, v);
    s = s * __expf(m - nm) + __expf(v - nm);
    m = nm;
  }
  redm[tid] = m; __syncthreads();
  for (int o = 512; o > 0; o >>= 1) { if (tid < o) redm[tid] = fmaxf(redm[tid], redm[tid + o]); __syncthreads(); }
  float M = redm[0];
  reds[tid] = s * __expf(m - M); __syncthreads();
  for (int o = 512; o > 0; o >>= 1) { if (tid < o) reds[tid] += reds[tid + o]; __syncthreads(); }
  float g = gate[r];
  float inv = (1.f - g) / reds[0];
  for (int c = tid; c < VEXT; c += 1024) {
    float v = (c < nv) ? __expf(row[c] - M) * inv : 0.f;
    row[c] = v;
  }
  __syncthreads();  // drain row writes before RMW on same lines
  if (tid < 256) {
    float v = g * atten[(long)r * 256 + tid];
    atomicAdd(row + sou[b * 256 + tid], v);
  }
}

extern "C" void kernel_launch(void* const* d_in, const int* in_sizes, int n_in,
                              void* d_out, int out_size, void* d_ws, size_t ws_size,
                              hipStream_t stream) {
  (void)in_sizes; (void)n_in; (void)out_size;
  const int* sou = (const int*)d_in[0];
  const int* tar = (const int*)d_in[1];
  const float* hidden = (const float*)d_in[2];
  const float* enc = (const float*)d_in[3];
  const int* ext = (const int*)d_in[4];
  const float* emb = (const float*)d_in[5];
  const float* wih = (const float*)d_in[6];
  const float* whh = (const float*)d_in[7];
  const float* bih = (const float*)d_in[8];
  const float* bhh = (const float*)d_in[9];
  const float* fc_enc_w = (const float*)d_in[10];
  const float* fc_enc_b = (const float*)d_in[11];
  const float* fc_dec_w = (const float*)d_in[12];
  const float* fc_dec_b = (const float*)d_in[13];
  const float* v_w = (const float*)d_in[14];
  const float* w1 = (const float*)d_in[15];
  const float* b1 = (const float*)d_in[16];
  const float* w2 = (const float*)d_in[17];
  const float* b2 = (const float*)d_in[18];
  const float* g1w = (const float*)d_in[19];
  const float* g1b = (const float*)d_in[20];
  const float* g2w = (const float*)d_in[21];
  const float* g2b = (const float*)d_in[22];
  const float* g3w = (const float*)d_in[23];
  const float* g3b = (const float*)d_in[24];
  float* out = (float*)d_out;

  char* base = (char*)d_ws;
  size_t cur = 0;
  auto alloc = [&](size_t bytes) -> void* {
    void* r = base + cur;
    cur = (cur + bytes + 255) & ~(size_t)255;
    return r;
  };
  u16* wihB = (u16*)alloc(6291456);     // [4][1536][512] bf16
  u16* whhB = (u16*)alloc(6291456);
  u16* w1B  = (u16*)alloc(51511296);    // [50304][512] bf16 (padded)
  u16* encB = (u16*)alloc(2097152);     // [2048][512]
  u16* fceB = (u16*)alloc(524288);      // [512][512]
  u16* fcdB = (u16*)alloc(524288);
  u16* fo2B = (u16*)alloc(1048576);     // [512][1024]
  u16* midB = (u16*)alloc(524288);      // [512][512] (400 real)
  u16* decB = (u16*)alloc(524288);
  u16* allB = (u16*)alloc(1048576);     // [512][1024]
  u16* xA0  = (u16*)alloc(917504);      // [896][512] bf16, row = t*16+row
  u16* xA1  = (u16*)alloc(917504);
  u16* xA2  = (u16*)alloc(917504);
  u16* xA3  = (u16*)alloc(917504);
  float* gi  = (float*)alloc(5505024);  // [896][1536] f32 (reused per layer)
  float* x4f = (float*)alloc(819200);   // [8][50][512]
  float* e1 = (float*)alloc(4194304);   // [2048][512]
  float* e2 = (float*)alloc(819200);    // [400][512]
  float* allo = (float*)alloc(1638400); // [400][1024]
  float* mid = (float*)alloc(819200);   // [400][512]
  float* g3dot = (float*)alloc(1600);
  float* gate = (float*)alloc(1600);
  int* lens = (int*)alloc(32);
  u16* hG = (u16*)alloc(32768);         // [2][8192] h exchange
  int* flags = (int*)alloc(1024);       // [4][50] + pad
  if (cur > ws_size) return;  // ws too small -> loud failure

  u16* xA[4] = {xA0, xA1, xA2, xA3};

  hipMemsetAsync(flags, 0, 1024, stream);

  // weight / input conversions to bf16
  k_conv<<<12288, 256, 0, stream>>>(wih, wihB, 3145728L, 3145728L);
  k_conv<<<12288, 256, 0, stream>>>(whh, whhB, 3145728L, 3145728L);
  k_conv<<<100608, 256, 0, stream>>>(w1, w1B, 25731072L, 25755648L);
  k_conv<<<4096, 256, 0, stream>>>(enc, encB, 1048576L, 1048576L);
  k_conv<<<1024, 256, 0, stream>>>(fc_enc_w, fceB, 262144L, 262144L);
  k_conv<<<1024, 256, 0, stream>>>(fc_dec_w, fcdB, 262144L, 262144L);
  k_conv<<<2048, 256, 0, stream>>>(w2, fo2B, 524288L, 524288L);
  k_prep<<<400, 256, 0, stream>>>(tar, emb, g3w, xA0, g3dot);
  k_zpad<<<800, 256, 0, stream>>>(xA0);
  k_lengths<<<1, 64, 0, stream>>>(tar, lens);

  // GRU: per layer, gi GEMM (all timesteps) then 4-CU recurrence
  for (int l = 0; l < 4; l++) {
    k_gemm_bf16<<<dim3(12, 7), 256, 0, stream>>>(
        xA[l], wihB + (long)l * 1536 * 512, bih + l * 1536, gi, 896, 1536, 512, 1536);
    k_rec4<<<4, 256, 0, stream>>>(
        whhB + (long)l * 1536 * 512, bhh + l * 1536, hidden + l * 4096, gi,
        (l < 3) ? xA[l + 1] : xA0, x4f, hG, flags + l * 64, (l == 3) ? 1 : 0);
  }
  k_mask<<<400, 256, 0, stream>>>(x4f, lens);
  k_conv<<<1024, 256, 0, stream>>>(x4f, decB, 204800L, 262144L);

  // attention path
  k_gemm_bf16<<<dim3(4, 16), 256, 0, stream>>>(encB, fceB, fc_enc_b, e1, 2048, 512, 512, 512);
  k_gemm_bf16<<<dim3(4, 4), 256, 0, stream>>>(decB, fcdB, fc_dec_b, e2, 400, 512, 512, 512);
  k_attn<<<400, 256, 0, stream>>>(e1, e2, enc, x4f, sou, v_w, g1w, g1b, g2w, g2b, g3b,
                                  g3dot, allo, gate, out + OUT_AT_OFF);
  k_conv<<<2048, 256, 0, stream>>>(allo, allB, 409600L, 524288L);
  k_gemm_bf16<<<dim3(4, 4), 256, 0, stream>>>(allB, fo2B, b2, mid, 400, 512, 1024, 512);
  k_conv<<<1024, 256, 0, stream>>>(mid, midB, 204800L, 262144L);

  // logits -> softmax(+scatter)
  k_gemm_bf16<<<dim3(393, 4), 256, 0, stream>>>(midB, w1B, b1, out, 400, 50256, 512, 50256);
  k_softsc<<<400, 1024, 0, stream>>>(out, gate, ext, out + OUT_AT_OFF, sou);
}